// Round 15
// 1188.266 us; speedup vs baseline: 8.3907x; 1.0470x over previous
//
#include <hip/hip_runtime.h>
#include <hip/hip_bf16.h>
#include <math.h>

#define NN 16384
#define NG 512
#define NE2 65536
#define NE3 393216
#define DEMB 300
#define DSCH 128
#define NRBF 50
#define NTAB 5120
#define TROWS 5121
#define DMAX 25.0f

typedef __attribute__((ext_vector_type(8))) short bf16x8;
typedef __attribute__((ext_vector_type(4))) float f32x4;

__device__ __forceinline__ float sspf(float x) {
  float sp = log1pf(expf(-fabsf(x))) + fmaxf(x, 0.f);
  return sp - 0.69314718055994530942f;
}

__device__ __forceinline__ short f2b(float f) {
  union { float f; unsigned u; } v;
  v.f = f;
  unsigned r = v.u + 0x7FFF + ((v.u >> 16) & 1);  // RNE
  return (short)(r >> 16);
}

__device__ __forceinline__ float b2f(unsigned short b) {
  union { unsigned u; float f; } v;
  v.u = ((unsigned)b) << 16;
  return v.f;
}

__device__ __forceinline__ unsigned pk2(float a, float b) {
  return ((unsigned)(unsigned short)f2b(b) << 16) | (unsigned short)f2b(a);
}

// ---------------- CSR build ----------------

__global__ void k_hist3(const int* __restrict__ ei2, const int* __restrict__ ei3,
                        const int* __restrict__ batch, int* __restrict__ cnt2,
                        int* __restrict__ cnt3, int* __restrict__ cntg) {
  int i = blockIdx.x * blockDim.x + threadIdx.x;
  if (i < NE2) {
    atomicAdd(&cnt2[ei2[NE2 + i]], 1);
  } else if (i < NE2 + NE3) {
    atomicAdd(&cnt3[ei3[NE3 + (i - NE2)]], 1);
  } else if (i < NE2 + NE3 + NN) {
    atomicAdd(&cntg[batch[i - NE2 - NE3]], 1);
  }
}

__global__ __launch_bounds__(1024) void k_scan3(const int* __restrict__ c0, int* __restrict__ o0,
                                                int n0, const int* __restrict__ c1,
                                                int* __restrict__ o1, int n1,
                                                const int* __restrict__ c2, int* __restrict__ o2,
                                                int n2) {
  const int* cnt = (blockIdx.x == 0) ? c0 : (blockIdx.x == 1) ? c1 : c2;
  int* off = (blockIdx.x == 0) ? o0 : (blockIdx.x == 1) ? o1 : o2;
  int n = (blockIdx.x == 0) ? n0 : (blockIdx.x == 1) ? n1 : n2;
  __shared__ int part[1024];
  int tid = threadIdx.x;
  int per = (n + 1023) / 1024;
  int base = tid * per;
  int sum = 0;
  for (int i = 0; i < per; ++i) {
    int idx = base + i;
    if (idx < n) sum += cnt[idx];
  }
  part[tid] = sum;
  __syncthreads();
  for (int d = 1; d < 1024; d <<= 1) {
    int v = (tid >= d) ? part[tid - d] : 0;
    __syncthreads();
    part[tid] += v;
    __syncthreads();
  }
  int run = (tid == 0) ? 0 : part[tid - 1];
  for (int i = 0; i < per; ++i) {
    int idx = base + i;
    if (idx < n) {
      off[idx] = run;
      run += cnt[idx];
    }
  }
  if (tid == 0) off[n] = part[1023];
}

__global__ void k_scatterB(const int* __restrict__ ei2, const int* __restrict__ ea2,
                           const int* __restrict__ batch, const int* __restrict__ off2,
                           int* __restrict__ cur2, int4* __restrict__ em2,
                           const int* __restrict__ ei3, const float* __restrict__ pos,
                           const int* __restrict__ off3, int* __restrict__ cur3,
                           int4* __restrict__ em3) {
  int i = blockIdx.x * blockDim.x + threadIdx.x;
  if (i < NE2) {
    int e = i;
    int s = ei2[e], d = ei2[NE2 + e];
    int p = atomicAdd(&cur2[d], 1);
    int j = off2[d] + p;
    em2[j] = make_int4(s, ea2[2 * e] * 4 + ea2[2 * e + 1], batch[s], 0);
  } else if (i < NE2 + NE3) {
    int e = i - NE2;
    int s = ei3[e], d = ei3[NE3 + e];
    float dx = pos[3 * d] - pos[3 * s];
    float dy = pos[3 * d + 1] - pos[3 * s + 1];
    float dz = pos[3 * d + 2] - pos[3 * s + 2];
    float dist = sqrtf(dx * dx + dy * dy + dz * dz);
    float u = fminf(dist * ((float)NTAB / DMAX), (float)NTAB - 0.001f);
    int idx = (int)u;
    int p = atomicAdd(&cur3[d], 1);
    int j = off3[d] + p;
    em3[j] = make_int4(s, idx, __float_as_int(u - (float)idx), 0);
  }
}

// ---------------- consolidated init kernels ----------------

__global__ void k_init_gin(const int* __restrict__ x2d, const float* __restrict__ e1,
                           const float* __restrict__ e2, short* __restrict__ hb,
                           const float* __restrict__ vni, float* __restrict__ vn,
                           short* __restrict__ vnb) {
  int i = blockIdx.x * blockDim.x + threadIdx.x;
  if (i < NN * DEMB) {
    int n = i / DEMB, c = i - n * DEMB;
    hb[i] = f2b(e1[x2d[2 * n] * DEMB + c] + e2[x2d[2 * n + 1] * DEMB + c]);
  } else if (i < NN * DEMB + NG * DEMB) {
    int j = i - NN * DEMB;
    float v = vni[j % DEMB];
    vn[j] = v;
    vnb[j] = f2b(v);
  }
}

__global__ void k_init_sch(float* __restrict__ rbs, float* __restrict__ Cs,
                           const int* __restrict__ z, const float* __restrict__ emb,
                           float* __restrict__ hs, short* __restrict__ hsb) {
  int i = blockIdx.x * blockDim.x + threadIdx.x;
  if (i < TROWS * NRBF) {
    int j = i / NRBF, k = i - j * NRBF;
    float dj = (float)j * (DMAX / (float)NTAB);
    const float step = 10.0f / 49.0f;
    const float coeff = -0.5f / (step * step);
    float t = dj - (float)k * step;
    rbs[i] = expf(coeff * t * t);
    if (k == 0) Cs[j] = 0.5f * (cosf(dj * (3.14159265358979323846f / 10.0f)) + 1.0f);
  } else if (i < TROWS * NRBF + NN * DSCH) {
    int j = i - TROWS * NRBF;
    float v = emb[z[j >> 7] * DSCH + (j & 127)];
    hs[j] = v;
    hsb[j] = f2b(v);
  }
}

// ---------------- gather aggregations ----------------

__device__ __forceinline__ void gin_edge_add(const unsigned* __restrict__ hr,
                                             const unsigned* __restrict__ vr,
                                             const unsigned* __restrict__ eu, int u0, int u1,
                                             int u2, bool has2, float* acc) {
  unsigned a = hr[u0], b = vr[u0], e = eu[u0];
  acc[0] += fmaxf(b2f((unsigned short)a) + b2f((unsigned short)b) + b2f((unsigned short)e), 0.f);
  acc[1] += fmaxf(b2f((unsigned short)(a >> 16)) + b2f((unsigned short)(b >> 16)) +
                      b2f((unsigned short)(e >> 16)), 0.f);
  a = hr[u1]; b = vr[u1]; e = eu[u1];
  acc[2] += fmaxf(b2f((unsigned short)a) + b2f((unsigned short)b) + b2f((unsigned short)e), 0.f);
  acc[3] += fmaxf(b2f((unsigned short)(a >> 16)) + b2f((unsigned short)(b >> 16)) +
                      b2f((unsigned short)(e >> 16)), 0.f);
  if (has2) {
    a = hr[u2]; b = vr[u2]; e = eu[u2];
    acc[4] += fmaxf(b2f((unsigned short)a) + b2f((unsigned short)b) + b2f((unsigned short)e), 0.f);
    acc[5] += fmaxf(b2f((unsigned short)(a >> 16)) + b2f((unsigned short)(b >> 16)) +
                        b2f((unsigned short)(e >> 16)), 0.f);
  }
}

__global__ __launch_bounds__(256) void k_gin_gather6(
    const short* __restrict__ hb, const short* __restrict__ vnb, const int* __restrict__ batch,
    const int* __restrict__ off2, const int4* __restrict__ em2, const float* __restrict__ bond1,
    const float* __restrict__ bond2, short* __restrict__ aggb) {
  __shared__ unsigned sb[18 * 150];
  int tid = threadIdx.x;
  for (int i = tid; i < 18 * 150; i += 256) {
    int c = i / 150, u = i - c * 150;
    int a0 = c / 3, a1 = c - a0 * 3;
    float v0 = bond1[a0 * 300 + 2 * u] + bond2[a1 * 300 + 2 * u];
    float v1 = bond1[a0 * 300 + 2 * u + 1] + bond2[a1 * 300 + 2 * u + 1];
    sb[i] = pk2(v0, v1);
  }
  __syncthreads();
  int d = blockIdx.x * 4 + (tid >> 6);
  int l = tid & 63;
  int j0 = off2[d], j1 = off2[d + 1];
  const unsigned* hu = (const unsigned*)hb + (size_t)d * 150;
  const unsigned* vu = (const unsigned*)vnb + (size_t)batch[d] * 150;
  const int u0 = l, u1 = l + 64, u2 = l + 128;
  const bool has2 = (u2 < 150);
  float acc[6];
  {
    unsigned a = hu[u0], b = vu[u0];
    acc[0] = b2f((unsigned short)a) + b2f((unsigned short)b);
    acc[1] = b2f((unsigned short)(a >> 16)) + b2f((unsigned short)(b >> 16));
    a = hu[u1]; b = vu[u1];
    acc[2] = b2f((unsigned short)a) + b2f((unsigned short)b);
    acc[3] = b2f((unsigned short)(a >> 16)) + b2f((unsigned short)(b >> 16));
    if (has2) {
      a = hu[u2]; b = vu[u2];
      acc[4] = b2f((unsigned short)a) + b2f((unsigned short)b);
      acc[5] = b2f((unsigned short)(a >> 16)) + b2f((unsigned short)(b >> 16));
    } else {
      acc[4] = acc[5] = 0.f;
    }
  }
  int j = j0;
  for (; j + 1 < j1; j += 2) {
    int4 mA = em2[j], mB = em2[j + 1];
    const unsigned* hrA = (const unsigned*)hb + (size_t)mA.x * 150;
    const unsigned* vrA = (const unsigned*)vnb + (size_t)mA.z * 150;
    const unsigned* euA = sb + ((mA.y >> 2) * 3 + (mA.y & 3)) * 150;
    const unsigned* hrB = (const unsigned*)hb + (size_t)mB.x * 150;
    const unsigned* vrB = (const unsigned*)vnb + (size_t)mB.z * 150;
    const unsigned* euB = sb + ((mB.y >> 2) * 3 + (mB.y & 3)) * 150;
    gin_edge_add(hrA, vrA, euA, u0, u1, u2, has2, acc);
    gin_edge_add(hrB, vrB, euB, u0, u1, u2, has2, acc);
  }
  if (j < j1) {
    int4 m = em2[j];
    gin_edge_add((const unsigned*)hb + (size_t)m.x * 150, (const unsigned*)vnb + (size_t)m.z * 150,
                 sb + ((m.y >> 2) * 3 + (m.y & 3)) * 150, u0, u1, u2, has2, acc);
  }
  unsigned* outu = (unsigned*)aggb + (size_t)d * 160;
  outu[u0] = pk2(acc[0], acc[1]);
  outu[u1] = pk2(acc[2], acc[3]);
  if (u2 < 160) outu[u2] = has2 ? pk2(acc[4], acc[5]) : 0u;
}

// CFConv: 2 waves per destination (contiguous edge halves), LDS combine
__global__ __launch_bounds__(256) void k_conv_gather6(
    const short* __restrict__ ftabb, const short* __restrict__ x1b, const int* __restrict__ off3,
    const int4* __restrict__ em3, short* __restrict__ agg3b) {
  __shared__ float2 sm[2][64];
  int tid = threadIdx.x;
  int slot = tid >> 7;        // which of 2 destinations in this block
  int wh = (tid >> 6) & 1;    // which wave of the pair
  int lane = tid & 63;
  int d = blockIdx.x * 2 + slot;
  int j0 = off3[d], j1 = off3[d + 1];
  int mid = j0 + ((j1 - j0 + 1) >> 1);
  int jb = wh ? mid : j0;
  int je = wh ? j1 : mid;
  float a0 = 0.f, a1 = 0.f;
  int j = jb;
  for (; j + 1 < je; j += 2) {
    int4 mA = em3[j], mB = em3[j + 1];
    float frA = __int_as_float(mA.z), frB = __int_as_float(mB.z);
    unsigned t0A = ((const unsigned*)(ftabb + (size_t)mA.y * 128))[lane];
    unsigned t1A = ((const unsigned*)(ftabb + (size_t)(mA.y + 1) * 128))[lane];
    unsigned xvA = ((const unsigned*)(x1b + (size_t)mA.x * 128))[lane];
    unsigned t0B = ((const unsigned*)(ftabb + (size_t)mB.y * 128))[lane];
    unsigned t1B = ((const unsigned*)(ftabb + (size_t)(mB.y + 1) * 128))[lane];
    unsigned xvB = ((const unsigned*)(x1b + (size_t)mB.x * 128))[lane];
    {
      float t0a = b2f((unsigned short)t0A), t0b = b2f((unsigned short)(t0A >> 16));
      float t1a = b2f((unsigned short)t1A), t1b = b2f((unsigned short)(t1A >> 16));
      a0 += (t0a + frA * (t1a - t0a)) * b2f((unsigned short)(xvA & 0xFFFF));
      a1 += (t0b + frA * (t1b - t0b)) * b2f((unsigned short)(xvA >> 16));
    }
    {
      float t0a = b2f((unsigned short)t0B), t0b = b2f((unsigned short)(t0B >> 16));
      float t1a = b2f((unsigned short)t1B), t1b = b2f((unsigned short)(t1B >> 16));
      a0 += (t0a + frB * (t1a - t0a)) * b2f((unsigned short)(xvB & 0xFFFF));
      a1 += (t0b + frB * (t1b - t0b)) * b2f((unsigned short)(xvB >> 16));
    }
  }
  if (j < je) {
    int4 m = em3[j];
    float fr = __int_as_float(m.z);
    unsigned t0 = ((const unsigned*)(ftabb + (size_t)m.y * 128))[lane];
    unsigned t1 = ((const unsigned*)(ftabb + (size_t)(m.y + 1) * 128))[lane];
    unsigned xv = ((const unsigned*)(x1b + (size_t)m.x * 128))[lane];
    float t0a = b2f((unsigned short)t0), t0b = b2f((unsigned short)(t0 >> 16));
    float t1a = b2f((unsigned short)t1), t1b = b2f((unsigned short)(t1 >> 16));
    a0 += (t0a + fr * (t1a - t0a)) * b2f((unsigned short)(xv & 0xFFFF));
    a1 += (t0b + fr * (t1b - t0b)) * b2f((unsigned short)(xv >> 16));
  }
  if (wh == 1) sm[slot][lane] = make_float2(a0, a1);
  __syncthreads();
  if (wh == 0) {
    float2 p = sm[slot][lane];
    ((unsigned*)(agg3b + (size_t)d * 128))[lane] = pk2(a0 + p.x, a1 + p.y);
  }
}

// fused: vnab[g][320] = bf16( sum_rows(hb) + vn[g] )
__global__ __launch_bounds__(256) void k_poolvn(const short* __restrict__ hb,
                                                const int* __restrict__ goff,
                                                const float* __restrict__ vn,
                                                short* __restrict__ vnab) {
  int g = blockIdx.x * 4 + (threadIdx.x >> 6);
  int l = threadIdx.x & 63;
  if (g >= NG) return;
  int r0 = goff[g], r1 = goff[g + 1];
  const int u0 = l, u1 = l + 64, u2 = l + 128;
  const bool has2 = (u2 < 150);
  float acc[6] = {};
  for (int r = r0; r < r1; ++r) {
    const unsigned* hu = (const unsigned*)hb + (size_t)r * 150;
    unsigned a = hu[u0];
    acc[0] += b2f((unsigned short)a);
    acc[1] += b2f((unsigned short)(a >> 16));
    a = hu[u1];
    acc[2] += b2f((unsigned short)a);
    acc[3] += b2f((unsigned short)(a >> 16));
    if (has2) {
      a = hu[u2];
      acc[4] += b2f((unsigned short)a);
      acc[5] += b2f((unsigned short)(a >> 16));
    }
  }
  const float2* v2 = (const float2*)(vn + (size_t)g * 300);
  unsigned* outu = (unsigned*)vnab + (size_t)g * 160;
  float2 w = v2[u0];
  outu[u0] = pk2(acc[0] + w.x, acc[1] + w.y);
  w = v2[u1];
  outu[u1] = pk2(acc[2] + w.x, acc[3] + w.y);
  if (u2 < 160) {
    if (has2) {
      w = v2[u2];
      outu[u2] = pk2(acc[4] + w.x, acc[5] + w.y);
    } else {
      outu[u2] = 0u;
    }
  }
}

// head pool (GIN): xcat[g][0:320]
__global__ __launch_bounds__(256) void k_poolhead2(const short* __restrict__ hb,
                                                   const int* __restrict__ goff,
                                                   short* __restrict__ xcat) {
  int g = blockIdx.x * 4 + (threadIdx.x >> 6);
  int l = threadIdx.x & 63;
  if (g >= NG) return;
  int r0 = goff[g], r1 = goff[g + 1];
  const int u0 = l, u1 = l + 64, u2 = l + 128;
  const bool has2 = (u2 < 150);
  float acc[6] = {};
  for (int r = r0; r < r1; ++r) {
    const unsigned* hu = (const unsigned*)hb + (size_t)r * 150;
    unsigned a = hu[u0];
    acc[0] += b2f((unsigned short)a);
    acc[1] += b2f((unsigned short)(a >> 16));
    a = hu[u1];
    acc[2] += b2f((unsigned short)a);
    acc[3] += b2f((unsigned short)(a >> 16));
    if (has2) {
      a = hu[u2];
      acc[4] += b2f((unsigned short)a);
      acc[5] += b2f((unsigned short)(a >> 16));
    }
  }
  float s = 1.0f / fmaxf((float)(r1 - r0), 1.0f);
  unsigned* outu = (unsigned*)xcat + (size_t)g * 224;
  outu[u0] = pk2(acc[0] * s, acc[1] * s);
  outu[u1] = pk2(acc[2] * s, acc[3] * s);
  if (u2 < 160) outu[u2] = has2 ? pk2(acc[4] * s, acc[5] * s) : 0u;
}

// head pool (SchNet): xcat[g][320:448]
__global__ __launch_bounds__(256) void k_poolhead3(const short* __restrict__ hsb,
                                                   const int* __restrict__ goff,
                                                   short* __restrict__ xcat) {
  int g = blockIdx.x * 4 + (threadIdx.x >> 6);
  int l = threadIdx.x & 63;
  if (g >= NG) return;
  int r0 = goff[g], r1 = goff[g + 1];
  float a0 = 0.f, a1 = 0.f;
  for (int r = r0; r < r1; ++r) {
    unsigned v = ((const unsigned*)hsb)[(size_t)r * 64 + l];
    a0 += b2f((unsigned short)(v & 0xFFFF));
    a1 += b2f((unsigned short)(v >> 16));
  }
  float s = 1.0f / fmaxf((float)(r1 - r0), 1.0f);
  ((unsigned*)xcat)[(size_t)g * 224 + 160 + l] = pk2(a0 * s, a1 * s);
}

// gate dot + sigmoid + blend
__global__ __launch_bounds__(256) void k_blend(const float* __restrict__ gh,
                                               const float* __restrict__ gW2,
                                               const float* __restrict__ gb2,
                                               const float* __restrict__ hcat,
                                               short* __restrict__ hfb) {
  int g = blockIdx.x * 4 + (threadIdx.x >> 6);
  int l = threadIdx.x & 63;
  if (g >= NG) return;
  float2 v = ((const float2*)(gh + (size_t)g * 128))[l];
  float dot = v.x * gW2[2 * l] + v.y * gW2[2 * l + 1];
  for (int m = 32; m; m >>= 1) dot += __shfl_xor(dot, m);
  float gg = 1.0f / (1.0f + expf(-(dot + gb2[0])));
  const float* hc = hcat + (size_t)g * 608;
  unsigned* outu = (unsigned*)hfb + (size_t)g * 160;
  const int u0 = l, u1 = l + 64, u2 = l + 128;
  float a0 = hc[2 * u0], a1 = hc[2 * u0 + 1], b0 = hc[304 + 2 * u0], b1 = hc[304 + 2 * u0 + 1];
  outu[u0] = pk2(gg * a0 + (1.f - gg) * b0, gg * a1 + (1.f - gg) * b1);
  a0 = hc[2 * u1]; a1 = hc[2 * u1 + 1]; b0 = hc[304 + 2 * u1]; b1 = hc[304 + 2 * u1 + 1];
  outu[u1] = pk2(gg * a0 + (1.f - gg) * b0, gg * a1 + (1.f - gg) * b1);
  if (u2 < 160) {
    if (u2 < 150) {
      a0 = hc[2 * u2]; a1 = hc[2 * u2 + 1]; b0 = hc[304 + 2 * u2]; b1 = hc[304 + 2 * u2 + 1];
      outu[u2] = pk2(gg * a0 + (1.f - gg) * b0, gg * a1 + (1.f - gg) * b1);
    } else {
      outu[u2] = 0u;
    }
  }
}

// ---------------- weight prep ----------------
__global__ void k_prepw2(const float* __restrict__ Wa, const float* __restrict__ Wb,
                         short* __restrict__ Wta, short* __restrict__ Wtb, int K, int N, int Kp,
                         int Np, int La, int Lb) {
  int i = blockIdx.x * blockDim.x + threadIdx.x;
  int per = Np * Kp;
  if (i >= (La + Lb) * per) return;
  int l = i / per, r = i - l * per;
  int n = r / Kp, k = r - n * Kp;
  const float* W = (l < La) ? Wa : Wb;
  int ll = (l < La) ? l : l - La;
  short* Wt = (l < La) ? Wta : Wtb;
  float v = (n < N && k < K) ? W[(size_t)ll * K * N + (size_t)k * N + n] : 0.f;
  Wt[(size_t)ll * per + r] = f2b(v);
}

__global__ void k_prepw3(const float* __restrict__ W0, const float* __restrict__ W1,
                         const float* __restrict__ W2, short* __restrict__ T0,
                         short* __restrict__ T1, short* __restrict__ T2) {
  int i = blockIdx.x * blockDim.x + threadIdx.x;
  const int per = 6 * 128 * 128;
  if (i >= 3 * per) return;
  int which = i / per, r = i - which * per;
  int l = r / 16384, rr = r - l * 16384;
  int n = rr / 128, k = rr - n * 128;
  const float* W = (which == 0) ? W0 : (which == 1) ? W1 : W2;
  short* T = (which == 0) ? T0 : (which == 1) ? T1 : T2;
  T[r] = f2b(W[(size_t)l * 16384 + (size_t)k * 128 + n]);
}

#define W1SZ (608 * 448)
#define G1SZ (128 * 608)
#define C1SZ (160 * 320)
#define C2SZ (12 * 160)
__global__ void k_prephead(const float* __restrict__ p2W, const float* __restrict__ p2b,
                           const float* __restrict__ p3W, const float* __restrict__ p3b,
                           const float* __restrict__ gW1, const float* __restrict__ cW1,
                           const float* __restrict__ cb1, const float* __restrict__ cW2,
                           short* __restrict__ Wcat, short* __restrict__ gW1cat,
                           short* __restrict__ cW1cat, short* __restrict__ cW2cat,
                           float* __restrict__ bcat, float* __restrict__ cb1p) {
  int i = blockIdx.x * blockDim.x + threadIdx.x;
  if (i < W1SZ) {
    int o = i / 448, k = i - o * 448;
    float v = 0.f;
    if (o < 300 && k < 300) v = p2W[(size_t)k * 300 + o];
    else if (o >= 304 && o < 604 && k >= 320) v = p3W[(size_t)(k - 320) * 300 + (o - 304)];
    Wcat[i] = f2b(v);
  } else if (i < W1SZ + G1SZ) {
    int r = i - W1SZ;
    int o = r / 608, k = r - o * 608;
    float v = 0.f;
    if (k < 300) v = gW1[(size_t)k * 128 + o];
    else if (k >= 304 && k < 604) v = gW1[(size_t)(300 + k - 304) * 128 + o];
    gW1cat[r] = f2b(v);
  } else if (i < W1SZ + G1SZ + C1SZ) {
    int r = i - W1SZ - G1SZ;
    int o = r / 320, k = r - o * 320;
    cW1cat[r] = f2b((o < 150 && k < 300) ? cW1[(size_t)k * 150 + o] : 0.f);
  } else if (i < W1SZ + G1SZ + C1SZ + C2SZ) {
    int r = i - W1SZ - G1SZ - C1SZ;
    int o = r / 160, k = r - o * 160;
    cW2cat[r] = f2b((k < 150) ? cW2[(size_t)k * 12 + o] : 0.f);
  } else if (i < W1SZ + G1SZ + C1SZ + C2SZ + 608) {
    int o = i - W1SZ - G1SZ - C1SZ - C2SZ;
    bcat[o] = (o < 300) ? p2b[o] : (o >= 304 && o < 604) ? p3b[o - 304] : 0.f;
  } else if (i < W1SZ + G1SZ + C1SZ + C2SZ + 608 + 160) {
    int o = i - W1SZ - G1SZ - C1SZ - C2SZ - 608;
    cb1p[o] = (o < 150) ? cb1[o] : 0.f;
  }
}

// ---------------- z-batched fp32 GEMM ----------------
template <int ACT>
__global__ __launch_bounds__(256) void k_gemmz(
    const float* __restrict__ A, const float* __restrict__ B, const float* __restrict__ bias,
    const float* __restrict__ rscale, float* __restrict__ Cout, short* __restrict__ Coutb,
    int M, int N, int K, int ldc, long strideA, long strideB, long strideBias, long strideC) {
  A += (size_t)blockIdx.z * strideA;
  B += (size_t)blockIdx.z * strideB;
  bias += (size_t)blockIdx.z * strideBias;
  __shared__ float sA[16][65];
  __shared__ float sB[16][64];
  int tid = threadIdx.x;
  int tx = tid & 15, ty = tid >> 4;
  int bm = blockIdx.y * 64, bn = blockIdx.x * 64;
  float acc[4][4] = {};
  for (int k0 = 0; k0 < K; k0 += 16) {
#pragma unroll
    for (int t = 0; t < 4; ++t) {
      int i = tid + t * 256;
      int m = i >> 4, kk = i & 15;
      int gm = bm + m, gk = k0 + kk;
      sA[kk][m] = (gm < M && gk < K) ? A[(size_t)gm * K + gk] : 0.f;
    }
#pragma unroll
    for (int t = 0; t < 4; ++t) {
      int i = tid + t * 256;
      int kk = i >> 6, n = i & 63;
      int gk = k0 + kk, gn = bn + n;
      sB[kk][n] = (gk < K && gn < N) ? B[(size_t)gk * N + gn] : 0.f;
    }
    __syncthreads();
#pragma unroll
    for (int kk = 0; kk < 16; ++kk) {
      float a[4], b[4];
#pragma unroll
      for (int i = 0; i < 4; ++i) a[i] = sA[kk][ty + 16 * i];
#pragma unroll
      for (int j = 0; j < 4; ++j) b[j] = sB[kk][tx + 16 * j];
#pragma unroll
      for (int i = 0; i < 4; ++i)
#pragma unroll
        for (int j = 0; j < 4; ++j) acc[i][j] = fmaf(a[i], b[j], acc[i][j]);
    }
    __syncthreads();
  }
#pragma unroll
  for (int i = 0; i < 4; ++i) {
    int gm = bm + ty + 16 * i;
    if (gm >= M) continue;
    float rs = rscale ? rscale[gm] : 1.0f;
#pragma unroll
    for (int j = 0; j < 4; ++j) {
      int gn = bn + tx + 16 * j;
      if (gn >= N) continue;
      float v = acc[i][j] + bias[gn];
      if (ACT == 1) v = fmaxf(v, 0.f);
      if (ACT == 2) v = sspf(v);
      v *= rs;
      if (Cout) Cout[(size_t)blockIdx.z * strideC + (size_t)gm * ldc + gn] = v;
      if (Coutb) Coutb[(size_t)blockIdx.z * strideC + (size_t)gm * ldc + gn] = f2b(v);
    }
  }
}

// ---------------- bf16 MFMA GEMM, 64x128 tile ----------------
template <int ACT>
__global__ __launch_bounds__(256) void k_mgemm_bf64(
    const short* __restrict__ Ab, const short* __restrict__ Wt, const float* __restrict__ bias,
    const float* __restrict__ scale, const float* __restrict__ shift,
    const float* __restrict__ Cin, float* __restrict__ Cout, short* __restrict__ Coutb,
    int M, int N, int Kp, int ldc, int ldcb, int Nb) {
  __shared__ short sA[64 * 32];
  const int tid = threadIdx.x;
  const int lane = tid & 63;
  const int w = tid >> 6;
  const int bm = blockIdx.y * 64, bn = blockIdx.x * 128;

  f32x4 acc[4][2] = {};

  const int sr = tid >> 2;
  const int sk = (tid & 3) * 8;
  const short* Arow = Ab + (size_t)(bm + sr) * Kp + sk;
  const int ssw = (sr + (sr >> 2)) & 3;
  const int s0 = tid & 3;
  bf16x8* sAv = (bf16x8*)sA;

  const int frow = lane & 15;
  const int fslot = lane >> 4;
  const short* Bbase = Wt + (size_t)(bn + w * 32 + (lane & 15)) * Kp + (fslot * 8);

  for (int k0 = 0; k0 < Kp; k0 += 32) {
    __syncthreads();
    sAv[sr * 4 + (s0 ^ ssw)] = *(const bf16x8*)(Arow + k0);
    __syncthreads();

    bf16x8 af[4], bfr[2];
#pragma unroll
    for (int mf = 0; mf < 4; ++mf) {
      int r = frow + mf * 16;
      af[mf] = sAv[r * 4 + (fslot ^ ((r + (r >> 2)) & 3))];
    }
#pragma unroll
    for (int nf = 0; nf < 2; ++nf) bfr[nf] = *(const bf16x8*)(Bbase + (size_t)nf * 16 * Kp + k0);
#pragma unroll
    for (int mf = 0; mf < 4; ++mf)
#pragma unroll
      for (int nf = 0; nf < 2; ++nf)
        acc[mf][nf] =
            __builtin_amdgcn_mfma_f32_16x16x32_bf16(af[mf], bfr[nf], acc[mf][nf], 0, 0, 0);
  }

  const int colbase = bn + w * 32 + (lane & 15);
  const int rowbase = bm + ((lane >> 4) << 2);
#pragma unroll
  for (int nf = 0; nf < 2; ++nf) {
    int col = colbase + nf * 16;
    bool cv = col < N;
    float bi = (bias && cv) ? bias[col] : 0.f;
    float sc = (scale && cv) ? scale[col] : 1.f;
    float sh = (shift && cv) ? shift[col] : 0.f;
#pragma unroll
    for (int mf = 0; mf < 4; ++mf) {
      f32x4 v = acc[mf][nf];
#pragma unroll
      for (int j = 0; j < 4; ++j) {
        int row = rowbase + mf * 16 + j;
        float x = v[j] + bi;
        if (scale) x = x * sc + sh;
        if (ACT == 1) x = fmaxf(x, 0.f);
        if (ACT == 2) x = sspf(x);
        if (Cin && cv) x += Cin[(size_t)row * ldc + col];
        if (Cout && cv) Cout[(size_t)row * ldc + col] = x;
        if (Coutb && col < Nb) Coutb[(size_t)row * ldcb + col] = cv ? f2b(x) : (short)0;
      }
    }
  }
}

// ---------------- fused SchNet layer ----------------
template <int LAST>
__global__ __launch_bounds__(256) void k_sch_fused(
    const short* __restrict__ agg3b, const short* __restrict__ W2t, const float* __restrict__ b2,
    const short* __restrict__ W3t, const float* __restrict__ b3, const short* __restrict__ W1n,
    float* __restrict__ hs, short* __restrict__ hsb, short* __restrict__ x1b) {
  __shared__ short sA[64 * 128];
  __shared__ short sY[64 * 128];
  const int tid = threadIdx.x;
  const int lane = tid & 63;
  const int w = tid >> 6;
  const int bm = blockIdx.x * 64;
  bf16x8* sAv = (bf16x8*)sA;
  bf16x8* sYv = (bf16x8*)sY;
  {
    int r = tid >> 2, q = tid & 3;
    int ssw = (r + (r >> 2)) & 3;
    const short* Arow = agg3b + (size_t)(bm + r) * 128 + q * 8;
#pragma unroll
    for (int c = 0; c < 4; ++c) sAv[r * 16 + c * 4 + (q ^ ssw)] = *(const bf16x8*)(Arow + c * 32);
  }
  __syncthreads();
  const int frow = lane & 15;
  const int fslot = lane >> 4;
  const int colw = w * 32 + (lane & 15);
  const int rw0 = (lane >> 4) << 2;
  {
    f32x4 acc[4][2] = {};
    const short* Bbase = W2t + (size_t)colw * 128 + fslot * 8;
#pragma unroll
    for (int c = 0; c < 4; ++c) {
      bf16x8 af[4], bfr[2];
#pragma unroll
      for (int mf = 0; mf < 4; ++mf) {
        int r = frow + mf * 16;
        af[mf] = sAv[r * 16 + c * 4 + (fslot ^ ((r + (r >> 2)) & 3))];
      }
#pragma unroll
      for (int nf = 0; nf < 2; ++nf) bfr[nf] = *(const bf16x8*)(Bbase + nf * 16 * 128 + c * 32);
#pragma unroll
      for (int mf = 0; mf < 4; ++mf)
#pragma unroll
        for (int nf = 0; nf < 2; ++nf)
          acc[mf][nf] =
              __builtin_amdgcn_mfma_f32_16x16x32_bf16(af[mf], bfr[nf], acc[mf][nf], 0, 0, 0);
    }
#pragma unroll
    for (int nf = 0; nf < 2; ++nf) {
      int cl = colw + nf * 16;
      float bi = b2[cl];
#pragma unroll
      for (int mf = 0; mf < 4; ++mf)
#pragma unroll
        for (int j = 0; j < 4; ++j) {
          int rw = rw0 + mf * 16 + j;
          float y = sspf(acc[mf][nf][j] + bi);
          int slot = (cl >> 5) * 4 + (((cl >> 3) & 3) ^ ((rw + (rw >> 2)) & 3));
          sY[rw * 128 + slot * 8 + (cl & 7)] = f2b(y);
        }
    }
  }
  __syncthreads();
  {
    f32x4 acc[4][2] = {};
    const short* Bbase = W3t + (size_t)colw * 128 + fslot * 8;
#pragma unroll
    for (int c = 0; c < 4; ++c) {
      bf16x8 af[4], bfr[2];
#pragma unroll
      for (int mf = 0; mf < 4; ++mf) {
        int r = frow + mf * 16;
        af[mf] = sYv[r * 16 + c * 4 + (fslot ^ ((r + (r >> 2)) & 3))];
      }
#pragma unroll
      for (int nf = 0; nf < 2; ++nf) bfr[nf] = *(const bf16x8*)(Bbase + nf * 16 * 128 + c * 32);
#pragma unroll
      for (int mf = 0; mf < 4; ++mf)
#pragma unroll
        for (int nf = 0; nf < 2; ++nf)
          acc[mf][nf] =
              __builtin_amdgcn_mfma_f32_16x16x32_bf16(af[mf], bfr[nf], acc[mf][nf], 0, 0, 0);
    }
#pragma unroll
    for (int nf = 0; nf < 2; ++nf) {
      int cl = colw + nf * 16;
      float bi = b3[cl];
#pragma unroll
      for (int mf = 0; mf < 4; ++mf)
#pragma unroll
        for (int j = 0; j < 4; ++j) {
          int rw = rw0 + mf * 16 + j;
          size_t gi = (size_t)(bm + rw) * 128 + cl;
          float x = acc[mf][nf][j] + bi + hs[gi];
          hs[gi] = x;
          short xb = f2b(x);
          hsb[gi] = xb;
          int slot = (cl >> 5) * 4 + (((cl >> 3) & 3) ^ ((rw + (rw >> 2)) & 3));
          sA[rw * 128 + slot * 8 + (cl & 7)] = xb;
        }
    }
  }
  if (LAST) return;
  __syncthreads();
  {
    f32x4 acc[4][2] = {};
    const short* Bbase = W1n + (size_t)colw * 128 + fslot * 8;
#pragma unroll
    for (int c = 0; c < 4; ++c) {
      bf16x8 af[4], bfr[2];
#pragma unroll
      for (int mf = 0; mf < 4; ++mf) {
        int r = frow + mf * 16;
        af[mf] = sAv[r * 16 + c * 4 + (fslot ^ ((r + (r >> 2)) & 3))];
      }
#pragma unroll
      for (int nf = 0; nf < 2; ++nf) bfr[nf] = *(const bf16x8*)(Bbase + nf * 16 * 128 + c * 32);
#pragma unroll
      for (int mf = 0; mf < 4; ++mf)
#pragma unroll
        for (int nf = 0; nf < 2; ++nf)
          acc[mf][nf] =
              __builtin_amdgcn_mfma_f32_16x16x32_bf16(af[mf], bfr[nf], acc[mf][nf], 0, 0, 0);
    }
#pragma unroll
    for (int nf = 0; nf < 2; ++nf) {
      int cl = colw + nf * 16;
#pragma unroll
      for (int mf = 0; mf < 4; ++mf)
#pragma unroll
        for (int j = 0; j < 4; ++j) {
          int rw = rw0 + mf * 16 + j;
          x1b[(size_t)(bm + rw) * 128 + cl] = f2b(acc[mf][nf][j]);
        }
    }
  }
}

// ---------------- host ----------------

static inline void run_mgemm_bf64(hipStream_t st, const short* Ab, const short* Wt,
                                  const float* bias, const float* scale, const float* shift,
                                  const float* Cin, float* Cout, short* Coutb, int M, int N,
                                  int Kp, int ldc, int ldcb, int Nb, int act) {
  dim3 grid((N + 127) / 128, M / 64);
  if (act == 0)
    k_mgemm_bf64<0><<<grid, 256, 0, st>>>(Ab, Wt, bias, scale, shift, Cin, Cout, Coutb, M, N, Kp,
                                          ldc, ldcb, Nb);
  else if (act == 1)
    k_mgemm_bf64<1><<<grid, 256, 0, st>>>(Ab, Wt, bias, scale, shift, Cin, Cout, Coutb, M, N, Kp,
                                          ldc, ldcb, Nb);
  else
    k_mgemm_bf64<2><<<grid, 256, 0, st>>>(Ab, Wt, bias, scale, shift, Cin, Cout, Coutb, M, N, Kp,
                                          ldc, ldcb, Nb);
}

extern "C" void kernel_launch(void* const* d_in, const int* in_sizes, int n_in, void* d_out,
                              int out_size, void* d_ws, size_t ws_size, hipStream_t stream) {
  const int* x2d = (const int*)d_in[0];
  const int* ei2 = (const int*)d_in[1];
  const int* ea2 = (const int*)d_in[2];
  const int* batch = (const int*)d_in[3];
  const int* z = (const int*)d_in[4];
  const float* pos = (const float*)d_in[5];
  const int* ei3 = (const int*)d_in[6];
  const float* atom_emb1 = (const float*)d_in[7];
  const float* atom_emb2 = (const float*)d_in[8];
  const float* vn_init = (const float*)d_in[9];
  const float* gin_W1 = (const float*)d_in[10];
  const float* gin_b1 = (const float*)d_in[11];
  const float* gin_W2 = (const float*)d_in[12];
  const float* gin_b2 = (const float*)d_in[13];
  const float* gin_bond1 = (const float*)d_in[14];
  const float* gin_bond2 = (const float*)d_in[15];
  const float* gin_gamma = (const float*)d_in[16];
  const float* gin_beta = (const float*)d_in[17];
  const float* vn_W1 = (const float*)d_in[18];
  const float* vn_b1 = (const float*)d_in[19];
  const float* vn_W2 = (const float*)d_in[20];
  const float* vn_b2 = (const float*)d_in[21];
  const float* sch_emb = (const float*)d_in[22];
  const float* s_mW1 = (const float*)d_in[23];
  const float* s_mb1 = (const float*)d_in[24];
  const float* s_mW2 = (const float*)d_in[25];
  const float* s_mb2 = (const float*)d_in[26];
  const float* s_lin1W = (const float*)d_in[27];
  const float* s_lin2W = (const float*)d_in[28];
  const float* s_lin2b = (const float*)d_in[29];
  const float* s_linW = (const float*)d_in[30];
  const float* s_linb = (const float*)d_in[31];
  const float* p2W = (const float*)d_in[32];
  const float* p2b = (const float*)d_in[33];
  const float* p3W = (const float*)d_in[34];
  const float* p3b = (const float*)d_in[35];
  const float* gW1 = (const float*)d_in[36];
  const float* gb1 = (const float*)d_in[37];
  const float* gW2 = (const float*)d_in[38];
  const float* gb2 = (const float*)d_in[39];
  const float* cW1 = (const float*)d_in[40];
  const float* cb1 = (const float*)d_in[41];
  const float* cW2 = (const float*)d_in[42];
  const float* cb2 = (const float*)d_in[43];

  float* ws = (float*)d_ws;
  // GIN phase
  short* hb = (short*)ws;
  short* aggb = (short*)(ws + 5000000);
  short* y1b = (short*)(ws + 7700000);
  // SchNet phase (aliases GIN region)
  float* rbs = ws + 400000;
  float* Cs = ws + 700000;
  float* t1all = ws + 800000;
  short* ftabb = (short*)(ws + 4800000);
  float* hs = ws + 8800000;
  short* x1b = (short*)(ws + 11000000);
  short* agg3b = (short*)(ws + 13200000);
  short* hsb = (short*)(ws + 15400000);
  // bf16 transposed weights
  short* W1t = (short*)(ws + 20000000);
  short* W2t = (short*)(ws + 20600000);
  short* s1t = (short*)(ws + 21200000);
  short* s2t = (short*)(ws + 21300000);
  short* s3t = (short*)(ws + 21400000);
  // CSR region
  int* I = (int*)(ws + 22000000);
  int* cnt2 = I + 0;
  int* cnt3 = I + 16384;
  int* cntg = I + 32768;
  int* cur2 = I + 33280;
  int* cur3 = I + 49664;  // zero region = 66048 ints
  int* off2 = I + 70000;
  int* off3 = I + 90000;
  int* goff = I + 110000;
  int4* em2 = (int4*)(I + 120000);
  int4* em3 = (int4*)(I + 400000);
  // vn-MLP bf16 weights + buffers
  short* vnW1t = (short*)(ws + 24000000);
  short* vnW2t = (short*)(ws + 24420000);
  short* vnab = (short*)(ws + 24900000);
  short* vnhb = (short*)(ws + 24990000);
  short* vnb = (short*)(ws + 25150000);
  // head buffers
  short* Wcat = (short*)(ws + 25300000);
  short* gW1cat = (short*)(ws + 25440000);
  short* cW1cat = (short*)(ws + 25480000);
  short* cW2cat = (short*)(ws + 25510000);
  float* bcat = ws + 25520000;
  float* cb1p = ws + 25521000;
  short* xcat = (short*)(ws + 25530000);
  float* hcat = ws + 25650000;
  short* hcatb = (short*)(ws + 25970000);
  float* gh = ws + 26130000;
  short* hfb = (short*)(ws + 26200000);
  short* c1b = (short*)(ws + 26290000);
  // persistent tail
  float* vn = ws + 28443136;

  // ---- weight prep ----
  k_prepw2<<<(9 * 640 * 320 + 255) / 256, 256, 0, stream>>>(gin_W1, vn_W1, W1t, vnW1t, 300, 600,
                                                            320, 640, 5, 4);
  k_prepw2<<<(9 * 384 * 608 + 255) / 256, 256, 0, stream>>>(gin_W2, vn_W2, W2t, vnW2t, 600, 300,
                                                            608, 384, 5, 4);
  k_prepw3<<<(3 * 6 * 16384 + 255) / 256, 256, 0, stream>>>(s_lin1W, s_lin2W, s_linW, s1t, s2t,
                                                            s3t);
  k_prephead<<<(W1SZ + G1SZ + C1SZ + C2SZ + 608 + 160 + 255) / 256, 256, 0, stream>>>(
      p2W, p2b, p3W, p3b, gW1, cW1, cb1, cW2, Wcat, gW1cat, cW1cat, cW2cat, bcat, cb1p);

  // ---- CSR build ----
  hipMemsetAsync(I, 0, 66048 * sizeof(int), stream);
  k_hist3<<<(NE2 + NE3 + NN + 255) / 256, 256, 0, stream>>>(ei2, ei3, batch, cnt2, cnt3, cntg);
  k_scan3<<<3, 1024, 0, stream>>>(cnt2, off2, 16384, cnt3, off3, 16384, cntg, goff, 512);
  k_scatterB<<<(NE2 + NE3 + 255) / 256, 256, 0, stream>>>(ei2, ea2, batch, off2, cur2, em2, ei3,
                                                          pos, off3, cur3, em3);

  // ---- GIN ----
  k_init_gin<<<(NN * DEMB + NG * DEMB + 255) / 256, 256, 0, stream>>>(x2d, atom_emb1, atom_emb2,
                                                                      hb, vn_init, vn, vnb);
  for (int l = 0; l < 5; ++l) {
    k_gin_gather6<<<NN / 4, 256, 0, stream>>>(hb, vnb, batch, off2, em2,
                                              gin_bond1 + l * 6 * DEMB, gin_bond2 + l * 3 * DEMB,
                                              aggb);
    run_mgemm_bf64(stream, aggb, W1t + (size_t)l * 640 * 320, gin_b1 + l * 600, nullptr, nullptr,
                   nullptr, nullptr, y1b, NN, 600, 320, 0, 608, 608, 1);
    run_mgemm_bf64(stream, y1b, W2t + (size_t)l * 384 * 608, gin_b2 + l * 300,
                   gin_gamma + l * 300, gin_beta + l * 300, nullptr, nullptr, hb, NN, 300, 608, 0,
                   300, 300, (l < 4) ? 1 : 0);
    if (l < 4) {
      k_poolvn<<<NG / 4, 256, 0, stream>>>(hb, goff, vn, vnab);
      run_mgemm_bf64(stream, vnab, vnW1t + (size_t)l * 640 * 320, vn_b1 + l * 600, nullptr,
                     nullptr, nullptr, nullptr, vnhb, NG, 600, 320, 0, 608, 608, 1);
      run_mgemm_bf64(stream, vnhb, vnW2t + (size_t)l * 384 * 608, vn_b2 + l * 300, nullptr,
                     nullptr, nullptr, vn, vnb, NG, 300, 608, 300, 300, 300, 1);
    }
  }
  k_poolhead2<<<NG / 4, 256, 0, stream>>>(hb, goff, xcat);  // before SchNet clobbers hb region

  // ---- SchNet ----
  k_init_sch<<<(TROWS * NRBF + NN * DSCH + 255) / 256, 256, 0, stream>>>(rbs, Cs, z, sch_emb, hs,
                                                                         hsb);
  {
    dim3 ga(2, (TROWS + 63) / 64, 6);
    k_gemmz<2><<<ga, 256, 0, stream>>>(rbs, s_mW1, s_mb1, nullptr, t1all, nullptr, TROWS, 128, 50,
                                       128, 0L, 50L * 128, 128L, (long)TROWS * 128);
    k_gemmz<0><<<ga, 256, 0, stream>>>(t1all, s_mW2, s_mb2, Cs, nullptr, ftabb, TROWS, 128, 128,
                                       128, (long)TROWS * 128, 128L * 128, 128L,
                                       (long)TROWS * 128);
  }
  run_mgemm_bf64(stream, hsb, s1t, nullptr, nullptr, nullptr, nullptr, nullptr, x1b, NN, 128, 128,
                 0, 128, 128, 0);
  for (int l = 0; l < 6; ++l) {
    k_conv_gather6<<<NN / 2, 256, 0, stream>>>(ftabb + (size_t)l * TROWS * 128, x1b, off3, em3,
                                               agg3b);
    if (l < 5)
      k_sch_fused<0><<<NN / 64, 256, 0, stream>>>(agg3b, s2t + (size_t)l * 16384,
                                                  s_lin2b + l * 128, s3t + (size_t)l * 16384,
                                                  s_linb + l * 128, s1t + (size_t)(l + 1) * 16384,
                                                  hs, hsb, x1b);
    else
      k_sch_fused<1><<<NN / 64, 256, 0, stream>>>(agg3b, s2t + (size_t)l * 16384,
                                                  s_lin2b + l * 128, s3t + (size_t)l * 16384,
                                                  s_linb + l * 128, s1t, hs, hsb, x1b);
  }
  k_poolhead3<<<NG / 4, 256, 0, stream>>>(hsb, goff, xcat);

  // ---- batched MFMA head ----
  run_mgemm_bf64(stream, xcat, Wcat, bcat, nullptr, nullptr, nullptr, hcat, hcatb, NG, 608, 448,
                 608, 608, 608, 0);
  run_mgemm_bf64(stream, hcatb, gW1cat, gb1, nullptr, nullptr, nullptr, gh, nullptr, NG, 128, 608,
                 128, 128, 0, 1);
  k_blend<<<NG / 4, 256, 0, stream>>>(gh, gW2, gb2, hcat, hfb);
  run_mgemm_bf64(stream, hfb, cW1cat, cb1p, nullptr, nullptr, nullptr, nullptr, c1b, NG, 160, 320,
                 0, 160, 160, 1);
  run_mgemm_bf64(stream, c1b, cW2cat, cb2, nullptr, nullptr, nullptr, (float*)d_out, nullptr, NG,
                 12, 160, 12, 12, 0, 0);
}